// Round 1
// baseline (1930.154 us; speedup 1.0000x reference)
//
#include <hip/hip_runtime.h>

#define DIM   256
#define KCB   8192
#define NTOK  32768
#define KC    32
#define NSPLIT 4
#define CODES_PER_SPLIT (KCB / NSPLIT)   // 2048

// ---------------- kernel 1: z = x @ W^T + b ----------------
// 64x64 tile, 256 threads, 4x4 per thread
__global__ __launch_bounds__(256) void k_linear(const float* __restrict__ x,
                                                const float* __restrict__ W,
                                                const float* __restrict__ bias,
                                                float* __restrict__ z) {
    __shared__ __align__(16) float xs[KC][64];
    __shared__ __align__(16) float wsh[KC][64];
    const int tid = threadIdx.x;
    const int tx = tid & 15, ty = tid >> 4;
    const int m0 = blockIdx.x * 64;
    const int e0 = blockIdx.y * 64;
    float acc[4][4] = {};
    for (int k0 = 0; k0 < DIM; k0 += KC) {
        // stage xs[k][m] from x[m0+m][k0+k]: 64*32 floats = 512 float4, 2/thread
        #pragma unroll
        for (int r = 0; r < 2; ++r) {
            int s = tid + r * 256;
            int m = s >> 3, dv = s & 7;
            float4 v = *(const float4*)&x[(size_t)(m0 + m) * DIM + k0 + dv * 4];
            xs[dv*4+0][m] = v.x; xs[dv*4+1][m] = v.y; xs[dv*4+2][m] = v.z; xs[dv*4+3][m] = v.w;
        }
        #pragma unroll
        for (int r = 0; r < 2; ++r) {
            int s = tid + r * 256;
            int e = s >> 3, dv = s & 7;
            float4 v = *(const float4*)&W[(size_t)(e0 + e) * DIM + k0 + dv * 4];
            wsh[dv*4+0][e] = v.x; wsh[dv*4+1][e] = v.y; wsh[dv*4+2][e] = v.z; wsh[dv*4+3][e] = v.w;
        }
        __syncthreads();
        #pragma unroll 8
        for (int k = 0; k < KC; ++k) {
            float4 a = *(const float4*)&xs[k][ty * 4];
            float4 b = *(const float4*)&wsh[k][tx * 4];
            float am[4] = {a.x, a.y, a.z, a.w};
            float bn[4] = {b.x, b.y, b.z, b.w};
            #pragma unroll
            for (int i = 0; i < 4; ++i)
                #pragma unroll
                for (int j = 0; j < 4; ++j) acc[i][j] += am[i] * bn[j];
        }
        __syncthreads();
    }
    #pragma unroll
    for (int i = 0; i < 4; ++i) {
        int m = m0 + ty * 4 + i;
        #pragma unroll
        for (int j = 0; j < 4; ++j) {
            int e = e0 + tx * 4 + j;
            z[(size_t)m * DIM + e] = acc[i][j] + bias[e];
        }
    }
}

// ---------------- kernel 2: cnorm[k] = ||codebook[k]||^2 ----------------
__global__ __launch_bounds__(256) void k_cnorm(const float* __restrict__ cb,
                                               float* __restrict__ cnorm) {
    int wave = (int)((blockIdx.x * blockDim.x + threadIdx.x) >> 6);
    int lane = threadIdx.x & 63;
    if (wave >= KCB) return;
    float4 v = *(const float4*)&cb[(size_t)wave * DIM + lane * 4];
    float s = v.x*v.x + v.y*v.y + v.z*v.z + v.w*v.w;
    #pragma unroll
    for (int off = 32; off; off >>= 1) s += __shfl_down(s, off);
    if (lane == 0) cnorm[wave] = s;
}

// ---------------- kernel 3: per-split argmin over codes ----------------
// 128 tokens x 128 codes tile; 256 threads; 8x8 register tile per thread.
__global__ __launch_bounds__(256) void k_argmin(const float* __restrict__ z,
                                                const float* __restrict__ cb,
                                                const float* __restrict__ cnorm,
                                                float* __restrict__ minval,
                                                int* __restrict__ minidx) {
    __shared__ __align__(16) float smem[2 * KC * 128];   // 32 KB
    float (*zs)[128] = (float(*)[128])smem;
    float (*cs)[128] = (float(*)[128])(smem + KC * 128);

    const int tid = threadIdx.x;
    const int tx = tid & 15, ty = tid >> 4;
    const int m0 = blockIdx.x * 128;
    const int split = blockIdx.y;
    const int nbase = split * CODES_PER_SPLIT;

    float best[8];
    int bidx[8];
    #pragma unroll
    for (int i = 0; i < 8; ++i) { best[i] = 3.4e38f; bidx[i] = 0x7fffffff; }

    for (int t = 0; t < CODES_PER_SPLIT; t += 128) {
        const int n0 = nbase + t;
        float acc[8][8] = {};
        for (int k0 = 0; k0 < DIM; k0 += KC) {
            // stage zs[k][m]: 128m x 32k = 1024 float4, 4/thread (coalesced global)
            #pragma unroll
            for (int r = 0; r < 4; ++r) {
                int s = tid + r * 256;
                int m = s >> 3, dv = s & 7;
                float4 v = *(const float4*)&z[(size_t)(m0 + m) * DIM + k0 + dv * 4];
                zs[dv*4+0][m] = v.x; zs[dv*4+1][m] = v.y; zs[dv*4+2][m] = v.z; zs[dv*4+3][m] = v.w;
            }
            // stage cs[k][n]
            #pragma unroll
            for (int r = 0; r < 4; ++r) {
                int s = tid + r * 256;
                int n = s >> 3, dv = s & 7;
                float4 v = *(const float4*)&cb[(size_t)(n0 + n) * DIM + k0 + dv * 4];
                cs[dv*4+0][n] = v.x; cs[dv*4+1][n] = v.y; cs[dv*4+2][n] = v.z; cs[dv*4+3][n] = v.w;
            }
            __syncthreads();
            #pragma unroll 8
            for (int k = 0; k < KC; ++k) {
                float4 a0 = *(const float4*)&zs[k][ty * 8];
                float4 a1 = *(const float4*)&zs[k][ty * 8 + 4];
                float4 b0 = *(const float4*)&cs[k][tx * 4];          // n-low group
                float4 b1 = *(const float4*)&cs[k][64 + tx * 4];     // n-high group
                float am[8] = {a0.x,a0.y,a0.z,a0.w,a1.x,a1.y,a1.z,a1.w};
                float bn[8] = {b0.x,b0.y,b0.z,b0.w,b1.x,b1.y,b1.z,b1.w};
                #pragma unroll
                for (int i = 0; i < 8; ++i)
                    #pragma unroll
                    for (int j = 0; j < 8; ++j) acc[i][j] += am[i] * bn[j];
            }
            __syncthreads();
        }
        // scores + running argmin; ascending n order preserves first-min semantics
        #pragma unroll
        for (int j = 0; j < 4; ++j) {
            int n = n0 + tx * 4 + j;
            float cn = cnorm[n];
            #pragma unroll
            for (int i = 0; i < 8; ++i) {
                float sc = cn - 2.0f * acc[i][j];
                if (sc < best[i]) { best[i] = sc; bidx[i] = n; }
            }
        }
        #pragma unroll
        for (int j = 0; j < 4; ++j) {
            int n = n0 + 64 + tx * 4 + j;
            float cn = cnorm[n];
            #pragma unroll
            for (int i = 0; i < 8; ++i) {
                float sc = cn - 2.0f * acc[i][4 + j];
                if (sc < best[i]) { best[i] = sc; bidx[i] = n; }
            }
        }
    }

    // cross-thread (tx) reduce per token row; alias staging LDS (dead after barrier)
    float (*rv)[17] = (float(*)[17])smem;                 // 128*17 floats
    int   (*ri)[17] = (int  (*)[17])(smem + 3072);
    #pragma unroll
    for (int i = 0; i < 8; ++i) { rv[ty * 8 + i][tx] = best[i]; ri[ty * 8 + i][tx] = bidx[i]; }
    __syncthreads();
    if (tid < 128) {
        int m = tid;
        float bv = rv[m][0]; int bi = ri[m][0];
        #pragma unroll
        for (int t2 = 1; t2 < 16; ++t2) {
            float v = rv[m][t2]; int ix = ri[m][t2];
            if (v < bv || (v == bv && ix < bi)) { bv = v; bi = ix; }
        }
        minval[(size_t)split * NTOK + m0 + m] = bv;
        minidx[(size_t)split * NTOK + m0 + m] = bi;
    }
}

// ---------------- kernel 4: merge splits, gather q, loss partials ----------------
// one wave per token; 4 tokens per 256-thread block; deterministic partials
__global__ __launch_bounds__(256) void k_finalize(const float* __restrict__ z,
                                                  const float* __restrict__ cb,
                                                  const float* __restrict__ minval,
                                                  const int* __restrict__ minidx,
                                                  float* __restrict__ out,
                                                  float* __restrict__ partials) {
    __shared__ float blk[4];
    int token = (int)((blockIdx.x * blockDim.x + threadIdx.x) >> 6);
    int lane = threadIdx.x & 63;
    int warp = threadIdx.x >> 6;
    if (token >= NTOK) return;

    float bv = minval[token]; int bi = minidx[token];
    #pragma unroll
    for (int s = 1; s < NSPLIT; ++s) {
        float v = minval[(size_t)s * NTOK + token];
        int ix = minidx[(size_t)s * NTOK + token];
        if (v < bv || (v == bv && ix < bi)) { bv = v; bi = ix; }
    }
    float4 zq = *(const float4*)&z[(size_t)token * DIM + lane * 4];
    float4 q  = *(const float4*)&cb[(size_t)bi * DIM + lane * 4];
    *(float4*)&out[(size_t)token * DIM + lane * 4] = q;   // x_recon == q (STE)
    float dx = zq.x - q.x, dy = zq.y - q.y, dz = zq.z - q.z, dw = zq.w - q.w;
    float s2 = dx*dx + dy*dy + dz*dz + dw*dw;
    #pragma unroll
    for (int off = 32; off; off >>= 1) s2 += __shfl_down(s2, off);
    if (lane == 0) blk[warp] = s2;
    __syncthreads();
    if (threadIdx.x == 0)
        partials[blockIdx.x] = blk[0] + blk[1] + blk[2] + blk[3];
}

// ---------------- kernel 5: reduce partials, write both losses ----------------
__global__ __launch_bounds__(256) void k_losses(const float* __restrict__ partials,
                                                float* __restrict__ out) {
    __shared__ float red[256];
    float s = 0.0f;
    for (int i = threadIdx.x; i < NTOK / 4; i += 256) s += partials[i];
    red[threadIdx.x] = s;
    __syncthreads();
    for (int off = 128; off; off >>= 1) {
        if ((int)threadIdx.x < off) red[threadIdx.x] += red[threadIdx.x + off];
        __syncthreads();
    }
    if (threadIdx.x == 0) {
        float l = red[0] / (float)((size_t)NTOK * DIM);
        out[(size_t)NTOK * DIM]     = l;  // dictionary_loss
        out[(size_t)NTOK * DIM + 1] = l;  // commitment_loss
    }
}

extern "C" void kernel_launch(void* const* d_in, const int* in_sizes, int n_in,
                              void* d_out, int out_size, void* d_ws, size_t ws_size,
                              hipStream_t stream) {
    const float* x  = (const float*)d_in[0];
    const float* W  = (const float*)d_in[1];
    const float* b  = (const float*)d_in[2];
    const float* cb = (const float*)d_in[3];
    float* out = (float*)d_out;

    char* ws = (char*)d_ws;
    float* z      = (float*)ws;                                      // 32 MB
    float* cnorm  = (float*)(ws + (size_t)NTOK * DIM * 4);           // 32 KB
    float* minval = (float*)(ws + (size_t)NTOK * DIM * 4 + 32768);   // 512 KB
    int*   minidx = (int*)  (ws + (size_t)NTOK * DIM * 4 + 32768 + (size_t)NSPLIT * NTOK * 4);
    float* parts  = (float*)(ws + (size_t)NTOK * DIM * 4 + 32768 + (size_t)2 * NSPLIT * NTOK * 4);

    k_linear<<<dim3(NTOK / 64, DIM / 64), 256, 0, stream>>>(x, W, b, z);
    k_cnorm<<<dim3(KCB / 4), 256, 0, stream>>>(cb, cnorm);
    k_argmin<<<dim3(NTOK / 128, NSPLIT), 256, 0, stream>>>(z, cb, cnorm, minval, minidx);
    k_finalize<<<dim3(NTOK / 4), 256, 0, stream>>>(z, cb, minval, minidx, out, parts);
    k_losses<<<1, 256, 0, stream>>>(parts, out);
}

// Round 2
// 683.524 us; speedup vs baseline: 2.8238x; 2.8238x over previous
//
#include <hip/hip_runtime.h>

#define DIM   256
#define KCB   8192
#define NTOK  32768
#define NSPLIT 4
#define CODES_PER_SPLIT (KCB / NSPLIT)   // 2048

using half8 = __attribute__((ext_vector_type(8))) _Float16;
using half4 = __attribute__((ext_vector_type(4))) _Float16;
using f32x4 = __attribute__((ext_vector_type(4))) float;

#define GLOBAL_AS(p) ((const __attribute__((address_space(1))) void*)(p))
#define LDS_AS(p)    ((__attribute__((address_space(3))) void*)(p))

__device__ __forceinline__ void ins2(float v, int i, float& b1v, int& b1i,
                                     float& b2v, int& b2i) {
    bool bet1 = (v < b1v) || (v == b1v && i < b1i);
    bool bet2 = (v < b2v) || (v == b2v && i < b2i);
    if (bet1) { b2v = b1v; b2i = b1i; b1v = v; b1i = i; }
    else if (bet2) { b2v = v; b2i = i; }
}

// ---------------- kernel 1: z = x @ W^T + b, stored as fp16 split (zh, zl) ----------------
__global__ __launch_bounds__(256) void k_linear(const float* __restrict__ x,
                                                const float* __restrict__ W,
                                                const float* __restrict__ bias,
                                                _Float16* __restrict__ zh,
                                                _Float16* __restrict__ zl) {
    __shared__ __align__(16) float xs[32][64];
    __shared__ __align__(16) float wsh[32][64];
    const int tid = threadIdx.x;
    const int tx = tid & 15, ty = tid >> 4;
    const int m0 = blockIdx.x * 64;
    const int e0 = blockIdx.y * 64;
    float acc[4][4] = {};
    for (int k0 = 0; k0 < DIM; k0 += 32) {
        #pragma unroll
        for (int r = 0; r < 2; ++r) {
            int s = tid + r * 256;
            int m = s >> 3, dv = s & 7;
            float4 v = *(const float4*)&x[(size_t)(m0 + m) * DIM + k0 + dv * 4];
            xs[dv*4+0][m] = v.x; xs[dv*4+1][m] = v.y; xs[dv*4+2][m] = v.z; xs[dv*4+3][m] = v.w;
        }
        #pragma unroll
        for (int r = 0; r < 2; ++r) {
            int s = tid + r * 256;
            int e = s >> 3, dv = s & 7;
            float4 v = *(const float4*)&W[(size_t)(e0 + e) * DIM + k0 + dv * 4];
            wsh[dv*4+0][e] = v.x; wsh[dv*4+1][e] = v.y; wsh[dv*4+2][e] = v.z; wsh[dv*4+3][e] = v.w;
        }
        __syncthreads();
        #pragma unroll 8
        for (int k = 0; k < 32; ++k) {
            float4 a = *(const float4*)&xs[k][ty * 4];
            float4 b = *(const float4*)&wsh[k][tx * 4];
            float am[4] = {a.x, a.y, a.z, a.w};
            float bn[4] = {b.x, b.y, b.z, b.w};
            #pragma unroll
            for (int i = 0; i < 4; ++i)
                #pragma unroll
                for (int j = 0; j < 4; ++j) acc[i][j] += am[i] * bn[j];
        }
        __syncthreads();
    }
    #pragma unroll
    for (int i = 0; i < 4; ++i) {
        int m = m0 + ty * 4 + i;
        float zv[4];
        #pragma unroll
        for (int j = 0; j < 4; ++j) zv[j] = acc[i][j] + bias[e0 + tx * 4 + j];
        half4 hh, hl;
        #pragma unroll
        for (int j = 0; j < 4; ++j) {
            _Float16 h = (_Float16)zv[j];
            hh[j] = h;
            hl[j] = (_Float16)(zv[j] - (float)h);
        }
        *(half4*)&zh[(size_t)m * DIM + e0 + tx * 4] = hh;
        *(half4*)&zl[(size_t)m * DIM + e0 + tx * 4] = hl;
    }
}

// ---------------- kernel 2: codebook -> (ch, cl) fp16 split + cnorm fp32 ----------------
__global__ __launch_bounds__(256) void k_split_cb(const float* __restrict__ cb,
                                                  _Float16* __restrict__ ch,
                                                  _Float16* __restrict__ cl,
                                                  float* __restrict__ cnorm) {
    int row = (int)((blockIdx.x * blockDim.x + threadIdx.x) >> 6);
    int lane = threadIdx.x & 63;
    if (row >= KCB) return;
    float4 v = *(const float4*)&cb[(size_t)row * DIM + lane * 4];
    float vv[4] = {v.x, v.y, v.z, v.w};
    half4 hh, hl;
    #pragma unroll
    for (int j = 0; j < 4; ++j) {
        _Float16 h = (_Float16)vv[j];
        hh[j] = h;
        hl[j] = (_Float16)(vv[j] - (float)h);
    }
    *(half4*)&ch[(size_t)row * DIM + lane * 4] = hh;
    *(half4*)&cl[(size_t)row * DIM + lane * 4] = hl;
    float s = v.x*v.x + v.y*v.y + v.z*v.z + v.w*v.w;
    #pragma unroll
    for (int m = 32; m; m >>= 1) s += __shfl_xor(s, m);
    if (lane == 0) cnorm[row] = s;
}

// ---------------- kernel 3: MFMA fp16x3 distance-argmin, top-2 per token per split ----------------
// 128 tokens x 128 codes tile, 4 waves (2x2), per-wave 4x4 of 16x16x32 MFMAs, 3 products each.
__global__ __launch_bounds__(256, 2) void k_argmin(const _Float16* __restrict__ zh,
                                                   const _Float16* __restrict__ zl,
                                                   const _Float16* __restrict__ ch,
                                                   const _Float16* __restrict__ cl,
                                                   const float* __restrict__ cnorm,
                                                   float4* __restrict__ cand) {
    __shared__ __align__(16) char smem[65536];
    _Float16 (*zh_s)[64] = (_Float16(*)[64])(smem);
    _Float16 (*zl_s)[64] = (_Float16(*)[64])(smem + 16384);
    _Float16 (*ch_s)[64] = (_Float16(*)[64])(smem + 32768);
    _Float16 (*cl_s)[64] = (_Float16(*)[64])(smem + 49152);

    const int tid = threadIdx.x;
    const int w = tid >> 6, lane = tid & 63;
    const int wm = w >> 1, wn = w & 1;
    const int m0 = blockIdx.x * 128;
    const int split = blockIdx.y;

    const int col = lane & 15;     // operand-local row (m or n within 16)
    const int kg  = lane >> 4;     // k-group 0..3

    // staging geometry: per instr 8 rows x 128 B; XOR-swizzle 16B chunks by (row&7)
    const int srow   = lane >> 3;
    const int schunk = (lane & 7) ^ (srow & 7);

    const _Float16* src = (w == 0) ? zh : (w == 1) ? zl : (w == 2) ? ch : cl;
    _Float16* dst = (w == 0) ? &zh_s[0][0] : (w == 1) ? &zl_s[0][0]
                  : (w == 2) ? &ch_s[0][0] : &cl_s[0][0];

    float val[16]; int idx[16];
    #pragma unroll
    for (int s = 0; s < 16; ++s) { val[s] = 3.4e38f; idx[s] = 0x7fffffff; }

    for (int t = 0; t < CODES_PER_SPLIT / 128; ++t) {
        const int n0 = split * CODES_PER_SPLIT + t * 128;
        const int rowbase = (w < 2) ? m0 : n0;
        f32x4 acc[4][4];
        #pragma unroll
        for (int mi = 0; mi < 4; ++mi)
            #pragma unroll
            for (int nj = 0; nj < 4; ++nj) acc[mi][nj] = (f32x4){0.f, 0.f, 0.f, 0.f};

        for (int k0 = 0; k0 < DIM; k0 += 64) {
            // async stage this wave's array: 16 instrs x 1KB
            #pragma unroll
            for (int j = 0; j < 16; ++j) {
                const _Float16* g = src + (size_t)(rowbase + j * 8 + srow) * DIM + k0 + schunk * 8;
                __builtin_amdgcn_global_load_lds(GLOBAL_AS(g), LDS_AS(dst + j * 512), 16, 0, 0);
            }
            __syncthreads();
            #pragma unroll
            for (int kk = 0; kk < 2; ++kk) {
                half8 ah[4], al[4], bh[4], bl[4];
                const int cbase = kk * 4 + kg;
                const int off = ((cbase ^ (col & 7)) * 8);
                #pragma unroll
                for (int mi = 0; mi < 4; ++mi) {
                    int r = wm * 64 + mi * 16 + col;
                    ah[mi] = *(const half8*)&zh_s[r][off];
                    al[mi] = *(const half8*)&zl_s[r][off];
                }
                #pragma unroll
                for (int nj = 0; nj < 4; ++nj) {
                    int r = wn * 64 + nj * 16 + col;
                    bh[nj] = *(const half8*)&ch_s[r][off];
                    bl[nj] = *(const half8*)&cl_s[r][off];
                }
                #pragma unroll
                for (int mi = 0; mi < 4; ++mi)
                    #pragma unroll
                    for (int nj = 0; nj < 4; ++nj) {
                        acc[mi][nj] = __builtin_amdgcn_mfma_f32_16x16x32_f16(ah[mi], bh[nj], acc[mi][nj], 0, 0, 0);
                        acc[mi][nj] = __builtin_amdgcn_mfma_f32_16x16x32_f16(ah[mi], bl[nj], acc[mi][nj], 0, 0, 0);
                        acc[mi][nj] = __builtin_amdgcn_mfma_f32_16x16x32_f16(al[mi], bh[nj], acc[mi][nj], 0, 0, 0);
                    }
            }
            __syncthreads();
        }
        // score + per-lane running argmin (ascending n per lane -> first-min kept)
        #pragma unroll
        for (int nj = 0; nj < 4; ++nj) {
            int n = n0 + wn * 64 + nj * 16 + col;
            float cn = cnorm[n];
            #pragma unroll
            for (int mi = 0; mi < 4; ++mi)
                #pragma unroll
                for (int r = 0; r < 4; ++r) {
                    float sc = fmaf(-2.0f, acc[mi][nj][r], cn);
                    int s = mi * 4 + r;
                    if (sc < val[s]) { val[s] = sc; idx[s] = n; }
                }
        }
    }

    // top-2 butterfly across the 16 lanes sharing each token row
    float b1[16], b2[16]; int i1[16], i2[16];
    #pragma unroll
    for (int s = 0; s < 16; ++s) { b1[s] = val[s]; i1[s] = idx[s]; b2[s] = 3.4e38f; i2[s] = 0x7ffffffe; }
    #pragma unroll
    for (int m = 1; m < 16; m <<= 1) {
        #pragma unroll
        for (int s = 0; s < 16; ++s) {
            float p1 = __shfl_xor(b1[s], m); int j1 = __shfl_xor(i1[s], m);
            float p2 = __shfl_xor(b2[s], m); int j2 = __shfl_xor(i2[s], m);
            ins2(p1, j1, b1[s], i1[s], b2[s], i2[s]);
            ins2(p2, j2, b1[s], i1[s], b2[s], i2[s]);
        }
    }
    // writer lanes (col==0) dump per-row top-2 into LDS (aliases staging, safe post-barrier)
    float4* cbuf = (float4*)smem;   // [128][2]
    if (col == 0) {
        #pragma unroll
        for (int s = 0; s < 16; ++s) {
            int mi = s >> 2, r = s & 3;
            int row = wm * 64 + mi * 16 + kg * 4 + r;
            float4 v; v.x = b1[s]; v.y = __int_as_float(i1[s]); v.z = b2[s]; v.w = __int_as_float(i2[s]);
            cbuf[row * 2 + wn] = v;
        }
    }
    __syncthreads();
    if (tid < 128) {
        float4 a = cbuf[tid * 2 + 0];
        float4 b = cbuf[tid * 2 + 1];
        float v1 = a.x; int j1 = __float_as_int(a.y);
        float v2 = a.z; int j2 = __float_as_int(a.w);
        ins2(b.x, __float_as_int(b.y), v1, j1, v2, j2);
        ins2(b.z, __float_as_int(b.w), v1, j1, v2, j2);
        float4 o; o.x = v1; o.y = __int_as_float(j1); o.z = v2; o.w = __int_as_float(j2);
        cand[(size_t)split * NTOK + m0 + tid] = o;
    }
}

// ---------------- kernel 4: merge splits, fp32 rescore top-2, gather q, loss partials ----------------
__global__ __launch_bounds__(256) void k_finalize(const _Float16* __restrict__ zh,
                                                  const _Float16* __restrict__ zl,
                                                  const float* __restrict__ cb,
                                                  const float* __restrict__ cnorm,
                                                  const float4* __restrict__ cand,
                                                  float* __restrict__ out,
                                                  float* __restrict__ partials) {
    __shared__ float blk[4];
    const int tid = threadIdx.x;
    const int w = tid >> 6, lane = tid & 63;
    const int token = blockIdx.x * 4 + w;

    float4 a = cand[token];
    float v1 = a.x; int j1 = __float_as_int(a.y);
    float v2 = a.z; int j2 = __float_as_int(a.w);
    #pragma unroll
    for (int s = 1; s < NSPLIT; ++s) {
        float4 b = cand[(size_t)s * NTOK + token];
        ins2(b.x, __float_as_int(b.y), v1, j1, v2, j2);
        ins2(b.z, __float_as_int(b.w), v1, j1, v2, j2);
    }

    // reconstruct z (fp16-pair sum: within 2^-22 of fp32 z)
    half4 hv = *(const half4*)&zh[(size_t)token * DIM + lane * 4];
    half4 lv = *(const half4*)&zl[(size_t)token * DIM + lane * 4];
    float z0 = (float)hv[0] + (float)lv[0];
    float z1 = (float)hv[1] + (float)lv[1];
    float z2 = (float)hv[2] + (float)lv[2];
    float z3 = (float)hv[3] + (float)lv[3];

    const float4* cb4 = (const float4*)cb;
    float4 e1 = cb4[(size_t)j1 * 64 + lane];
    float4 e2 = cb4[(size_t)j2 * 64 + lane];
    float s1 = z0 * e1.x + z1 * e1.y + z2 * e1.z + z3 * e1.w;
    float s2 = z0 * e2.x + z1 * e2.y + z2 * e2.z + z3 * e2.w;
    #pragma unroll
    for (int m = 32; m; m >>= 1) { s1 += __shfl_xor(s1, m); s2 += __shfl_xor(s2, m); }
    float d1 = cnorm[j1] - 2.0f * s1;
    float d2 = cnorm[j2] - 2.0f * s2;
    bool take1 = (d1 < d2) || (d1 == d2 && j1 < j2);
    float4 q = take1 ? e1 : e2;

    *(float4*)&out[(size_t)token * DIM + lane * 4] = q;   // x_recon == q (STE)

    float dx = z0 - q.x, dy = z1 - q.y, dz = z2 - q.z, dw = z3 - q.w;
    float ss = dx*dx + dy*dy + dz*dz + dw*dw;
    #pragma unroll
    for (int m = 32; m; m >>= 1) ss += __shfl_xor(ss, m);
    if (lane == 0) blk[w] = ss;
    __syncthreads();
    if (tid == 0) partials[blockIdx.x] = blk[0] + blk[1] + blk[2] + blk[3];
}

// ---------------- kernel 5: reduce partials, write both losses ----------------
__global__ __launch_bounds__(256) void k_losses(const float* __restrict__ partials,
                                                float* __restrict__ out) {
    __shared__ float red[256];
    float s = 0.0f;
    for (int i = threadIdx.x; i < NTOK / 4; i += 256) s += partials[i];
    red[threadIdx.x] = s;
    __syncthreads();
    for (int off = 128; off; off >>= 1) {
        if ((int)threadIdx.x < off) red[threadIdx.x] += red[threadIdx.x + off];
        __syncthreads();
    }
    if (threadIdx.x == 0) {
        float l = red[0] / (float)((size_t)NTOK * DIM);
        out[(size_t)NTOK * DIM]     = l;  // dictionary_loss
        out[(size_t)NTOK * DIM + 1] = l;  // commitment_loss
    }
}

extern "C" void kernel_launch(void* const* d_in, const int* in_sizes, int n_in,
                              void* d_out, int out_size, void* d_ws, size_t ws_size,
                              hipStream_t stream) {
    const float* x  = (const float*)d_in[0];
    const float* W  = (const float*)d_in[1];
    const float* b  = (const float*)d_in[2];
    const float* cb = (const float*)d_in[3];
    float* out = (float*)d_out;

    char* ws = (char*)d_ws;
    size_t off = 0;
    _Float16* zh = (_Float16*)(ws + off); off += (size_t)NTOK * DIM * 2;   // 16 MB
    _Float16* zl = (_Float16*)(ws + off); off += (size_t)NTOK * DIM * 2;   // 16 MB
    _Float16* ch = (_Float16*)(ws + off); off += (size_t)KCB * DIM * 2;    // 4 MB
    _Float16* cl = (_Float16*)(ws + off); off += (size_t)KCB * DIM * 2;    // 4 MB
    float* cnorm = (float*)(ws + off);    off += (size_t)KCB * 4;          // 32 KB
    float4* cand = (float4*)(ws + off);   off += (size_t)NSPLIT * NTOK * 16; // 2 MB
    float* parts = (float*)(ws + off);

    k_linear<<<dim3(NTOK / 64, DIM / 64), 256, 0, stream>>>(x, W, b, zh, zl);
    k_split_cb<<<dim3(KCB / 4), 256, 0, stream>>>(cb, ch, cl, cnorm);
    k_argmin<<<dim3(NTOK / 128, NSPLIT), 256, 0, stream>>>(zh, zl, ch, cl, cnorm, cand);
    k_finalize<<<dim3(NTOK / 4), 256, 0, stream>>>(zh, zl, cb, cnorm, cand, out, parts);
    k_losses<<<1, 256, 0, stream>>>(parts, out);
}